// Round 12
// baseline (1675.935 us; speedup 1.0000x reference)
//
#include <hip/hip_runtime.h>
#include <hip/hip_bf16.h>
#include <hip/hip_fp8.h>
#include <math.h>

// Problem constants
#define V_    8000
#define E_    150
#define LD_   50
#define H_    512
#define B_    100
#define T_    50
#define D0_   200   // E_+LD_
#define BT_   5000  // B_*T_
#define NV_   8000
#define KXP_  224   // padded layer-0 input K (200 -> 224)

typedef __attribute__((ext_vector_type(8))) short short8v;
typedef __attribute__((ext_vector_type(4))) float f32x4;
typedef __attribute__((ext_vector_type(2))) long long2v;

__device__ __forceinline__ float sigmoidf_(float x) { return 1.0f / (1.0f + expf(-x)); }
__device__ __forceinline__ unsigned short f2b(float x) {
    __hip_bfloat16 b = __float2bfloat16(x);
    return *(unsigned short*)&b;
}
__device__ __forceinline__ unsigned char f2e4(float x) {
    __hip_fp8_e4m3 v(x);           // OCP e4m3fn
    return (unsigned char)v.__x;
}
// async global->LDS: 64 lanes x 16B, lds dest = uniform base + lane*16
__device__ __forceinline__ void gload16(const void* g, void* l) {
    __builtin_amdgcn_global_load_lds(
        (__attribute__((address_space(1))) void*)(g),
        (__attribute__((address_space(3))) void*)(l), 16, 0, 0);
}

// ---------------- row L2-normalize
__global__ __launch_bounds__(256) void norm_rows(const float* __restrict__ in,
                                                 float* __restrict__ out, int R, int C) {
    int row = blockIdx.x;
    if (row >= R) return;
    int tid = threadIdx.x;
    float v = (tid < C) ? in[(size_t)row * C + tid] : 0.f;
    __shared__ float red[256];
    red[tid] = v * v;
    __syncthreads();
    for (int s = 128; s > 0; s >>= 1) {
        if (tid < s) red[tid] += red[tid + s];
        __syncthreads();
    }
    float scale = rsqrtf(fmaxf(red[0], 1e-12f));
    if (tid < C) out[(size_t)row * C + tid] = v * scale;
}

// ---------------- build xsb bf16 [m=t*100+b][KXP_], cols >=200 zero
__global__ void build_xsb(const int* __restrict__ inp, const int* __restrict__ langs,
                          const float* __restrict__ nemb, const float* __restrict__ nlang,
                          unsigned short* __restrict__ xsb) {
    int idx = blockIdx.x * 256 + threadIdx.x;
    if (idx >= BT_ * KXP_) return;
    int m = idx / KXP_, e = idx % KXP_;
    int b = m % 100, t = m / 100;
    float v = 0.f;
    if (e < E_)       v = nemb[(size_t)inp[b * T_ + t] * E_ + e];
    else if (e < D0_) v = nlang[(size_t)langs[b] * LD_ + (e - E_)];
    xsb[idx] = f2b(v);
}

// ---------------- pack fp32 weight into bf16 MFMA B-frag layout; rows >= klim are 0
__global__ __launch_bounds__(256) void pack_frags(const float* __restrict__ W, int ldw,
                                                  int k0off, int KT, int NT,
                                                  unsigned short* __restrict__ dst, int klim) {
    int idx = blockIdx.x * 256 + threadIdx.x;
    if (idx >= KT * NT * 64) return;
    int lane = idx & 63;
    int tile = idx >> 6;
    int nt = tile % NT, kt = tile / NT;
    int n = nt * 16 + (lane & 15);
    int kb = k0off + kt * 32 + (lane >> 4) * 8;
    unsigned short o[8];
#pragma unroll
    for (int j = 0; j < 8; ++j)
        o[j] = (kb + j < klim) ? f2b(W[(size_t)(kb + j) * ldw + n]) : 0;
    *(uint4*)(dst + (size_t)idx * 8) = *(const uint4*)o;
}

// ---------------- pack fp32 weight into fp8-e4m3 B-frag layout, PAIRED kt tiles:
// 16B at (((kt>>1)*NT + nt)*64 + lane)*16 holds kt-even frag (j<8) then kt-odd frag.
__global__ __launch_bounds__(256) void pack_frags8(const float* __restrict__ W, int ldw,
                                                   int k0off, int KT, int NT,
                                                   unsigned char* __restrict__ dst,
                                                   float scale) {
    int idx = blockIdx.x * 256 + threadIdx.x;
    if (idx >= KT * NT * 64) return;
    int lane = idx & 63;
    int tile = idx >> 6;
    int nt = tile % NT, kt = tile / NT;
    int n = nt * 16 + (lane & 15);
    int kb = k0off + kt * 32 + (lane >> 4) * 8;
    unsigned char o[8];
#pragma unroll
    for (int j = 0; j < 8; ++j) o[j] = f2e4(W[(size_t)(kb + j) * ldw + n] * scale);
    size_t off = ((((size_t)(kt >> 1) * NT + nt) * 64 + lane) << 4) + ((kt & 1) << 3);
    *(unsigned long long*)(dst + off) = *(const unsigned long long*)o;
}

// ---------------- fp8 MFMA phase: 2KB subgroups, ring-4 LDS buffers, restage-first,
// exact counted vmcnt. NSUB subs; SPK = subs per ktp (2 -> sub covers half a ktp group).
// Each sub = 2 gload16 (2KB) and 2 b-tiles (TPS=2). K = NSUB/SPK * 64.
template<int NSUB, int SPK>
__device__ __forceinline__ void mm_sub(const unsigned char* gsrc0, int NT,
                                       const unsigned char* a0, unsigned char* wst,
                                       int laneoff, int aoffB, f32x4* acc) {
    const size_t gstride = (size_t)NT * 1024;   // bytes per ktp group (whole block)
    // prologue: subs 0..2
#pragma unroll
    for (int s = 0; s < 3; ++s) {
        const int ktp = (SPK == 2) ? (s >> 1) : s;
        const int h = (SPK == 2) ? (s & 1) : 0;
        const unsigned char* g = gsrc0 + (size_t)ktp * gstride + h * 2048;
        gload16(g, wst + (s & 3) * 2048);
        gload16(g + 1024, wst + (s & 3) * 2048 + 1024);
    }
    __builtin_amdgcn_sched_barrier(0);
#pragma unroll
    for (int s = 0; s < NSUB; ++s) {
        // restage sub s+3 (into the buffer consumed at iter s-1; its reads drained below)
        if (s + 3 < NSUB) {
            const int s3 = s + 3;
            const int ktp3 = (SPK == 2) ? (s3 >> 1) : s3;
            const int h3 = (SPK == 2) ? (s3 & 1) : 0;
            const unsigned char* g = gsrc0 + (size_t)ktp3 * gstride + h3 * 2048;
            gload16(g, wst + (s3 & 3) * 2048);
            gload16(g + 1024, wst + (s3 & 3) * 2048 + 1024);
            __builtin_amdgcn_sched_barrier(0);
        }
        // wait for sub s: newer stage-loads = 2 * min(3, NSUB-1-s)
        {
            const int newer = (NSUB - 1 - s) < 3 ? (NSUB - 1 - s) : 3;
            if (newer == 3)      asm volatile("s_waitcnt vmcnt(6)" ::: "memory");
            else if (newer == 2) asm volatile("s_waitcnt vmcnt(4)" ::: "memory");
            else if (newer == 1) asm volatile("s_waitcnt vmcnt(2)" ::: "memory");
            else                 asm volatile("s_waitcnt vmcnt(0)" ::: "memory");
        }
        __builtin_amdgcn_sched_barrier(0);
        const int ktp = (SPK == 2) ? (s >> 1) : s;
        const int h = (SPK == 2) ? (s & 1) : 0;
        long av0 = *(const long*)(a0 + aoffB + (2 * ktp) * 32);
        long av1 = *(const long*)(a0 + aoffB + (2 * ktp + 1) * 32);
        const unsigned char* lb = wst + (s & 3) * 2048;
        long2v bv0 = *(const long2v*)(lb + laneoff);
        long2v bv1 = *(const long2v*)(lb + 1024 + laneoff);
        acc[h * 2 + 0] = __builtin_amdgcn_mfma_f32_16x16x32_fp8_fp8(av0, bv0.x, acc[h * 2 + 0], 0, 0, 0);
        acc[h * 2 + 0] = __builtin_amdgcn_mfma_f32_16x16x32_fp8_fp8(av1, bv0.y, acc[h * 2 + 0], 0, 0, 0);
        acc[h * 2 + 1] = __builtin_amdgcn_mfma_f32_16x16x32_fp8_fp8(av0, bv1.x, acc[h * 2 + 1], 0, 0, 0);
        acc[h * 2 + 1] = __builtin_amdgcn_mfma_f32_16x16x32_fp8_fp8(av1, bv1.y, acc[h * 2 + 1], 0, 0, 0);
        // WAR fence: drain this iter's ds reads before next iter's restage overwrites buf
        asm volatile("s_waitcnt lgkmcnt(0)" ::: "memory");
        __builtin_amdgcn_sched_barrier(0);
    }
}

// ---------------- one-layer GRU pass (fp8 weights, LDS-staged, fp32 master state):
// 50 blocks x 2 batch rows, 1024 threads (16 waves). Weights 0.75 MB/step (L2-resident).
// acc = (16h)@(32W) = 512*(h@W) -> epilogue scales by 1/512. Output houtb bf16 [m][512].
#define INV512_ 0.001953125f
__global__ __launch_bounds__(1024) void rnn_pass8(
    const float* __restrict__ Xg, const float* __restrict__ Xc,
    const unsigned char* __restrict__ Wgf, const unsigned char* __restrict__ Wcf,
    unsigned short* __restrict__ houtb) {
    __shared__ __align__(16) unsigned char hb8[16 * 520];
    __shared__ __align__(16) unsigned char rhb8[16 * 520];
    __shared__ float hf[2 * 512], uf[2 * 512];
    __shared__ __align__(16) unsigned char wstage[16 * 8192];   // 128KB: per-wave 4x2KB ring
    const int tid = threadIdx.x;
    const int w = tid >> 6, lane = tid & 63;   // w in 0..15
    const int arow = lane & 15;
    const int laneoff = lane * 16;
    const int aoffB = arow * 520 + (lane >> 4) * 8;
    const int rb = blockIdx.x * 2;
    unsigned char* wst = wstage + (w << 13);
    const unsigned char* gA = Wgf + ((size_t)(w * 4) * 64) * 16 + laneoff;   // phase A slice
    const unsigned char* gB = Wcf + ((size_t)(w * 2) * 64) * 16 + laneoff;   // phase B slice

    for (int i = tid; i < 16 * 520; i += 1024) { hb8[i] = 0; rhb8[i] = 0; }
    for (int i = tid; i < 2 * 512; i += 1024) hf[i] = 0.f;
    __syncthreads();

    for (int t = 0; t < T_; ++t) {
        const int m0 = t * 100 + rb, m1 = m0 + 1;
        {   // phase A: gates [N=1024, K=512]; wave w owns n-tiles w*4..w*4+3
            float xg0v[4], xg1v[4];
            if (lane < 16) {   // issue Xg loads first (oldest -> retired by first wait)
#pragma unroll
                for (int nt = 0; nt < 4; ++nt) {
                    int col = (w * 4 + nt) * 16 + arow;
                    xg0v[nt] = Xg[(size_t)m0 * 1024 + col];
                    xg1v[nt] = Xg[(size_t)m1 * 1024 + col];
                }
            }
            __builtin_amdgcn_sched_barrier(0);
            f32x4 acc[4];
#pragma unroll
            for (int nt = 0; nt < 4; ++nt) acc[nt] = (f32x4){0.f, 0.f, 0.f, 0.f};
            mm_sub<16, 2>(gA, 64, hb8, wst, laneoff, aoffB, acc);
            if (lane < 16) {
#pragma unroll
                for (int nt = 0; nt < 4; ++nt) {
                    int col = (w * 4 + nt) * 16 + arow;
                    float s0 = sigmoidf_(fmaf(acc[nt][0], INV512_, xg0v[nt]));
                    float s1 = sigmoidf_(fmaf(acc[nt][1], INV512_, xg1v[nt]));
                    if (col < 512) {
                        rhb8[col]       = f2e4(16.f * s0 * hf[col]);
                        rhb8[520 + col] = f2e4(16.f * s1 * hf[512 + col]);
                    } else {
                        uf[col - 512] = s0;
                        uf[col]       = s1;
                    }
                }
            }
        }
        __syncthreads();
        {   // phase B: candidate + h update [N=512, K=512]; wave w owns n-tiles w*2..w*2+1
            float xc0v[2], xc1v[2];
            if (lane < 16) {
#pragma unroll
                for (int nt = 0; nt < 2; ++nt) {
                    int col = (w * 2 + nt) * 16 + arow;
                    xc0v[nt] = Xc[(size_t)m0 * 512 + col];
                    xc1v[nt] = Xc[(size_t)m1 * 512 + col];
                }
            }
            __builtin_amdgcn_sched_barrier(0);
            f32x4 acc[2];
#pragma unroll
            for (int nt = 0; nt < 2; ++nt) acc[nt] = (f32x4){0.f, 0.f, 0.f, 0.f};
            mm_sub<8, 1>(gB, 32, rhb8, wst, laneoff, aoffB, acc);
            if (lane < 16) {
#pragma unroll
                for (int nt = 0; nt < 2; ++nt) {
                    int col = (w * 2 + nt) * 16 + arow;
                    float c0 = tanhf(fmaf(acc[nt][0], INV512_, xc0v[nt]));
                    float c1 = tanhf(fmaf(acc[nt][1], INV512_, xc1v[nt]));
                    float uA = uf[col], uB = uf[512 + col];
                    float hA = uA * hf[col] + (1.f - uA) * c0;
                    float hB = uB * hf[512 + col] + (1.f - uB) * c1;
                    hf[col] = hA; hf[512 + col] = hB;
                    hb8[col] = f2e4(16.f * hA); hb8[520 + col] = f2e4(16.f * hB);
                    houtb[(size_t)m0 * 512 + col] = f2b(hA);
                    houtb[(size_t)m1 * 512 + col] = f2b(hB);
                }
            }
        }
        __syncthreads();
    }
}

// ---------------- batched MFMA x-projection GEMM: C[M][N] = Abf[M][LDA] @ Wf + bias
template<int NTW, int KT, int LDA>
__global__ __launch_bounds__(256) void xproj_mfma(const unsigned short* __restrict__ Abf,
                                                  const unsigned short* __restrict__ Wf,
                                                  const float* __restrict__ bias,
                                                  float* __restrict__ C, int M) {
    const int NT = NTW * 4;
    const int N = NT * 16;
    const int tid = threadIdx.x;
    const int w = tid >> 6, lane = tid & 63;
    const int arow = lane & 15, hi = lane >> 4;
    const int mbase = blockIdx.x * 16;
    int ga = mbase + arow; if (ga >= M) ga = M - 1;      // clamp reads; stores guarded
    const unsigned short* ap = Abf + (size_t)ga * LDA + hi * 8;
    f32x4 acc[NTW];
#pragma unroll
    for (int nt = 0; nt < NTW; ++nt) acc[nt] = (f32x4){0.f, 0.f, 0.f, 0.f};
#pragma unroll 2
    for (int kt = 0; kt < KT; ++kt) {
        short8v af = *(const short8v*)(ap + kt * 32);
        const unsigned short* wp = Wf + ((size_t)(kt * NT + w * NTW) * 64 + lane) * 8;
#pragma unroll
        for (int nt = 0; nt < NTW; ++nt) {
            short8v bf = *(const short8v*)(wp + (size_t)nt * 512);
            acc[nt] = __builtin_amdgcn_mfma_f32_16x16x32_bf16(af, bf, acc[nt], 0, 0, 0);
        }
    }
#pragma unroll
    for (int nt = 0; nt < NTW; ++nt) {
        int col = (w * NTW + nt) * 16 + arow;
        float bb = bias[col];
#pragma unroll
        for (int q = 0; q < 4; ++q) {
            int gm = mbase + hi * 4 + q;
            if (gm < M) C[(size_t)gm * N + col] = acc[nt][q] + bb;
        }
    }
}

// ---------------- MFMA fused softmax GEMM + LSE partials + target pick
__global__ __launch_bounds__(256) void lse_mfma(const unsigned short* __restrict__ Abf,
                                                const unsigned short* __restrict__ swf,
                                                const float* __restrict__ sb,
                                                const int* __restrict__ tgt,
                                                float* __restrict__ zt,
                                                float* __restrict__ parts) {
    const int tid = threadIdx.x;
    const int w = tid >> 6, lane = tid & 63;
    const int arow = lane & 15, hi = lane >> 4;
    const int mbase = blockIdx.y * 64 + w * 16;          // wave-private 16-row M-tile
    const int ntg0 = blockIdx.x * 4;                     // 4 n-tiles = 64 cols
    int ga = mbase + arow; if (ga >= BT_) ga = BT_ - 1;  // clamp reads
    const unsigned short* ap = Abf + (size_t)ga * 512 + hi * 8;
    f32x4 acc[4];
#pragma unroll
    for (int nt = 0; nt < 4; ++nt) acc[nt] = (f32x4){0.f, 0.f, 0.f, 0.f};
#pragma unroll 2
    for (int kt = 0; kt < 16; ++kt) {
        short8v af = *(const short8v*)(ap + kt * 32);
        const unsigned short* wp = swf + ((size_t)(kt * 500 + ntg0) * 64 + lane) * 8;
#pragma unroll
        for (int nt = 0; nt < 4; ++nt) {
            short8v bf = *(const short8v*)(wp + (size_t)nt * 512);
            acc[nt] = __builtin_amdgcn_mfma_f32_16x16x32_bf16(af, bf, acc[nt], 0, 0, 0);
        }
    }
#pragma unroll
    for (int nt = 0; nt < 4; ++nt) {
        float bb = sb[(ntg0 + nt) * 16 + arow];
#pragma unroll
        for (int q = 0; q < 4; ++q) acc[nt][q] += bb;
    }
#pragma unroll
    for (int q = 0; q < 4; ++q) {
        int gr = mbase + hi * 4 + q;
        if (gr < BT_) {
            int tg = tgt[(gr % 100) * 50 + gr / 100];
            int lt = tg - arow;
#pragma unroll
            for (int nt = 0; nt < 4; ++nt)
                if (lt == (ntg0 + nt) * 16) zt[gr] = acc[nt][q];
        }
    }
    float lm[4], ls[4];
#pragma unroll
    for (int q = 0; q < 4; ++q)
        lm[q] = fmaxf(fmaxf(acc[0][q], acc[1][q]), fmaxf(acc[2][q], acc[3][q]));
#pragma unroll
    for (int mask = 1; mask < 16; mask <<= 1)
#pragma unroll
        for (int q = 0; q < 4; ++q) lm[q] = fmaxf(lm[q], __shfl_xor(lm[q], mask));
#pragma unroll
    for (int q = 0; q < 4; ++q) {
        float s = 0.f;
#pragma unroll
        for (int nt = 0; nt < 4; ++nt) s += expf(acc[nt][q] - lm[q]);
        ls[q] = s;
    }
#pragma unroll
    for (int mask = 1; mask < 16; mask <<= 1)
#pragma unroll
        for (int q = 0; q < 4; ++q) ls[q] += __shfl_xor(ls[q], mask);
    if (arow == 0) {
#pragma unroll
        for (int q = 0; q < 4; ++q) {
            int gr = mbase + hi * 4 + q;
            if (gr < BT_) {
                parts[(size_t)gr * 250 + blockIdx.x * 2 + 0] = lm[q];
                parts[(size_t)gr * 250 + blockIdx.x * 2 + 1] = ls[q];
            }
        }
    }
}

// ---------------- merge partials -> NLL -> block sums
__global__ __launch_bounds__(128) void final_nll(const float* __restrict__ parts,
                                                 const float* __restrict__ zt,
                                                 float* __restrict__ bsum) {
    int i = blockIdx.x * 128 + threadIdx.x;
    float nll = 0.f;
    if (i < BT_) {
        const float* p = parts + (size_t)i * 250;
        float M = p[0];
        for (int j = 1; j < 125; ++j) M = fmaxf(M, p[2 * j]);
        float S = 0.f;
        for (int j = 0; j < 125; ++j) S += p[2 * j + 1] * expf(p[2 * j] - M);
        nll = M + logf(S) - zt[i];
    }
    __shared__ float red[128];
    red[threadIdx.x] = nll;
    __syncthreads();
    for (int s = 64; s > 0; s >>= 1) {
        if (threadIdx.x < s) red[threadIdx.x] += red[threadIdx.x + s];
        __syncthreads();
    }
    if (threadIdx.x == 0) bsum[blockIdx.x] = red[0];
}

__global__ __launch_bounds__(64) void final_sum(const float* __restrict__ bsum,
                                                float* __restrict__ out) {
    int tid = threadIdx.x;
    float v = (tid < 40) ? bsum[tid] : 0.f;
    for (int off = 32; off > 0; off >>= 1) v += __shfl_down(v, off);
    if (tid == 0) out[0] = v / 5000.0f;
}

extern "C" void kernel_launch(void* const* d_in, const int* in_sizes, int n_in,
                              void* d_out, int out_size, void* d_ws, size_t ws_size,
                              hipStream_t stream) {
    const int*   inp   = (const int*)d_in[0];
    const int*   langs = (const int*)d_in[1];
    const int*   tgt   = (const int*)d_in[2];
    const float* emb   = (const float*)d_in[3];
    const float* lemb  = (const float*)d_in[4];
    const float* Wg0   = (const float*)d_in[5];
    const float* bg0   = (const float*)d_in[6];
    const float* Wc0   = (const float*)d_in[7];
    const float* bc0   = (const float*)d_in[8];
    const float* Wg1   = (const float*)d_in[9];
    const float* bg1   = (const float*)d_in[10];
    const float* Wc1   = (const float*)d_in[11];
    const float* bc1   = (const float*)d_in[12];
    const float* sw    = (const float*)d_in[13];
    const float* sb    = (const float*)d_in[14];
    float* out = (float*)d_out;

    // workspace layout (floats), max offset ~11.19M floats = 44.8 MB
    float* w = (float*)d_ws;
    // region A [0 .. 1,200,000 fl): nemb, later aliased by packed recurrent/x1 frags
    float* nemb = w;
    unsigned char* a8 = (unsigned char*)w;
    unsigned char* Wg0f8  = a8;                          //   524,288 B (fp8, paired kt)
    unsigned char* Wc0f8  = a8 + 524288;                 //   262,144 B
    unsigned char* Wg1hf8 = a8 + 786432;                 //   524,288 B
    unsigned char* Wc1hf8 = a8 + 1310720;                //   262,144 B (ends 1,572,864 B)
    unsigned short* Wg1xf = (unsigned short*)(a8 + 1572864);   // 524,288 u16
    unsigned short* Wc1xf = Wg1xf + 524288;                    // 262,144 u16 (ends 3,145,728 B)
    float* nlang = w + 1200000;             // 512
    // xsb bf16 [5000][224] @1,200,512 (560,000 fl), then layer-0 x-side bf16 frags
    unsigned short* xsb   = (unsigned short*)(w + 1200512);    // 1,120,000 u16
    unsigned short* Wg0xf = (unsigned short*)(w + 1760512);    //   229,376 u16 (114,688 fl)
    unsigned short* Wc0xf = (unsigned short*)(w + 1875200);    //   114,688 u16 ( 57,344 fl)
    // region B @2200512 (5.12M fl): Xg0 -> Xg1 (alias) -> swf (alias, after pass2)
    float* Xg0   = w + 2200512;
    float* Xg1   = w + 2200512;
    unsigned short* swf = (unsigned short*)(w + 2200512);      // 8,192,000 u16
    // region C @7320512 (2.56M fl): Xc0 -> Xc1 (alias) -> parts/zt/bsum (alias)
    float* Xc0   = w + 7320512;
    float* Xc1   = w + 7320512;
    float* parts = w + 7320512;             // 1,250,000
    float* ztb   = w + 7320512 + 1250000;   // 5,000
    float* bsum  = w + 7320512 + 1255000;   // 64
    // region D @9880512: h0seq bf16 -> h1o bf16 (alias)
    unsigned short* h0seq = (unsigned short*)(w + 9880512);    // 2,621,440 u16
    unsigned short* h1o   = (unsigned short*)(w + 9880512);    // 2,560,000 u16

    norm_rows<<<V_, 256, 0, stream>>>(emb, nemb, V_, E_);
    norm_rows<<<10, 256, 0, stream>>>(lemb, nlang, 10, LD_);
    build_xsb<<<(BT_ * KXP_ + 255) / 256, 256, 0, stream>>>(inp, langs, nemb, nlang, xsb);
    // pack recurrent weight slices to fp8 (scale 32); x-side & lse to bf16 (over dead nemb)
    pack_frags8<<<256, 256, 0, stream>>>(Wg0, 1024, D0_, 16, 64, Wg0f8, 32.f);
    pack_frags8<<<128, 256, 0, stream>>>(Wc0,  512, D0_, 16, 32, Wc0f8, 32.f);
    pack_frags8<<<256, 256, 0, stream>>>(Wg1, 1024, 512, 16, 64, Wg1hf8, 32.f);
    pack_frags8<<<128, 256, 0, stream>>>(Wc1,  512, 512, 16, 32, Wc1hf8, 32.f);
    pack_frags<<<256, 256, 0, stream>>>(Wg1, 1024, 0, 16, 64, Wg1xf, 1 << 30);
    pack_frags<<<128, 256, 0, stream>>>(Wc1,  512, 0, 16, 32, Wc1xf, 1 << 30);
    pack_frags<<<112, 256, 0, stream>>>(Wg0, 1024, 0, 7, 64, Wg0xf, D0_);   // x-part, K=224 pad
    pack_frags<<<56, 256, 0, stream>>>(Wc0,  512, 0, 7, 32, Wc0xf, D0_);
    // layer-0 input projections (bf16 MFMA, K=224)
    xproj_mfma<16, 7, KXP_><<<313, 256, 0, stream>>>(xsb, Wg0xf, bg0, Xg0, BT_);
    xproj_mfma<8, 7, KXP_><<<313, 256, 0, stream>>>(xsb, Wc0xf, bc0, Xc0, BT_);
    // pass 1: layer-0 recurrence (fp8 weights, LDS ring-4) -> h0seq (bf16)
    rnn_pass8<<<50, 1024, 0, stream>>>(Xg0, Xc0, Wg0f8, Wc0f8, h0seq);
    // layer-1 input projections from h0seq (bf16 MFMA, K=512)
    xproj_mfma<16, 16, 512><<<313, 256, 0, stream>>>(h0seq, Wg1xf, bg1, Xg1, BT_);
    xproj_mfma<8, 16, 512><<<313, 256, 0, stream>>>(h0seq, Wc1xf, bc1, Xc1, BT_);
    // pass 2: layer-1 recurrence (fp8 weights, LDS ring-4) -> h1o (bf16)
    rnn_pass8<<<50, 1024, 0, stream>>>(Xg1, Xc1, Wg1hf8, Wc1hf8, h1o);
    // pack softmax weights to bf16 frags (over dead Xg1)
    pack_frags<<<2000, 256, 0, stream>>>(sw, NV_, 0, 16, 500, swf, 1 << 30);
    // fused MFMA softmax GEMM + LSE partials + target pick (parts over dead Xc1)
    lse_mfma<<<dim3(125, 79), 256, 0, stream>>>(h1o, swf, sb, tgt, ztb, parts);
    final_nll<<<40, 128, 0, stream>>>(parts, ztb, bsum);
    final_sum<<<1, 64, 0, stream>>>(bsum, out);
}

// Round 13
// 1647.633 us; speedup vs baseline: 1.0172x; 1.0172x over previous
//
#include <hip/hip_runtime.h>
#include <hip/hip_bf16.h>
#include <hip/hip_fp8.h>
#include <math.h>

// Problem constants
#define V_    8000
#define E_    150
#define LD_   50
#define H_    512
#define B_    100
#define T_    50
#define D0_   200   // E_+LD_
#define BT_   5000  // B_*T_
#define NV_   8000
#define KXP_  224   // padded layer-0 input K (200 -> 224)

typedef __attribute__((ext_vector_type(8))) short short8v;
typedef __attribute__((ext_vector_type(4))) float f32x4;
typedef __attribute__((ext_vector_type(2))) long long2v;

__device__ __forceinline__ float sigmoidf_(float x) { return 1.0f / (1.0f + expf(-x)); }
__device__ __forceinline__ unsigned short f2b(float x) {
    __hip_bfloat16 b = __float2bfloat16(x);
    return *(unsigned short*)&b;
}
__device__ __forceinline__ unsigned char f2e4(float x) {
    __hip_fp8_e4m3 v(x);           // OCP e4m3fn
    return (unsigned char)v.__x;
}
// async global->LDS: 64 lanes x 16B, lds dest = uniform base + lane*16
__device__ __forceinline__ void gload16(const void* g, void* l) {
    __builtin_amdgcn_global_load_lds(
        (__attribute__((address_space(1))) void*)(g),
        (__attribute__((address_space(3))) void*)(l), 16, 0, 0);
}

// ---------------- row L2-normalize
__global__ __launch_bounds__(256) void norm_rows(const float* __restrict__ in,
                                                 float* __restrict__ out, int R, int C) {
    int row = blockIdx.x;
    if (row >= R) return;
    int tid = threadIdx.x;
    float v = (tid < C) ? in[(size_t)row * C + tid] : 0.f;
    __shared__ float red[256];
    red[tid] = v * v;
    __syncthreads();
    for (int s = 128; s > 0; s >>= 1) {
        if (tid < s) red[tid] += red[tid + s];
        __syncthreads();
    }
    float scale = rsqrtf(fmaxf(red[0], 1e-12f));
    if (tid < C) out[(size_t)row * C + tid] = v * scale;
}

// ---------------- build xsb bf16 [m=t*100+b][KXP_], cols >=200 zero
__global__ void build_xsb(const int* __restrict__ inp, const int* __restrict__ langs,
                          const float* __restrict__ nemb, const float* __restrict__ nlang,
                          unsigned short* __restrict__ xsb) {
    int idx = blockIdx.x * 256 + threadIdx.x;
    if (idx >= BT_ * KXP_) return;
    int m = idx / KXP_, e = idx % KXP_;
    int b = m % 100, t = m / 100;
    float v = 0.f;
    if (e < E_)       v = nemb[(size_t)inp[b * T_ + t] * E_ + e];
    else if (e < D0_) v = nlang[(size_t)langs[b] * LD_ + (e - E_)];
    xsb[idx] = f2b(v);
}

// ---------------- pack fp32 weight into bf16 MFMA B-frag layout; rows >= klim are 0
__global__ __launch_bounds__(256) void pack_frags(const float* __restrict__ W, int ldw,
                                                  int k0off, int KT, int NT,
                                                  unsigned short* __restrict__ dst, int klim) {
    int idx = blockIdx.x * 256 + threadIdx.x;
    if (idx >= KT * NT * 64) return;
    int lane = idx & 63;
    int tile = idx >> 6;
    int nt = tile % NT, kt = tile / NT;
    int n = nt * 16 + (lane & 15);
    int kb = k0off + kt * 32 + (lane >> 4) * 8;
    unsigned short o[8];
#pragma unroll
    for (int j = 0; j < 8; ++j)
        o[j] = (kb + j < klim) ? f2b(W[(size_t)(kb + j) * ldw + n]) : 0;
    *(uint4*)(dst + (size_t)idx * 8) = *(const uint4*)o;
}

// ---------------- pack fp32 weight into fp8-e4m3 B-frag layout, PAIRED kt tiles:
// 16B at (((kt>>1)*NT + nt)*64 + lane)*16 holds kt-even frag (j<8) then kt-odd frag.
__global__ __launch_bounds__(256) void pack_frags8(const float* __restrict__ W, int ldw,
                                                   int k0off, int KT, int NT,
                                                   unsigned char* __restrict__ dst,
                                                   float scale) {
    int idx = blockIdx.x * 256 + threadIdx.x;
    if (idx >= KT * NT * 64) return;
    int lane = idx & 63;
    int tile = idx >> 6;
    int nt = tile % NT, kt = tile / NT;
    int n = nt * 16 + (lane & 15);
    int kb = k0off + kt * 32 + (lane >> 4) * 8;
    unsigned char o[8];
#pragma unroll
    for (int j = 0; j < 8; ++j) o[j] = f2e4(W[(size_t)(kb + j) * ldw + n] * scale);
    size_t off = ((((size_t)(kt >> 1) * NT + nt) * 64 + lane) << 4) + ((kt & 1) << 3);
    *(unsigned long long*)(dst + off) = *(const unsigned long long*)o;
}

// ---------------- one-layer GRU pass (fp8 weights, LDS ring-2 with cross-phase
// prestage + raw s_barrier; vmcnt never drains to 0 in the loop):
// 50 blocks x 2 batch rows, 1024 threads (16 waves). Per-block group rotation
// (rot = bid&7) de-correlates the cross-CU same-line weight bursts.
// acc = (16h)@(32W) = 512*(h@W) -> epilogue scales by 1/512. Output houtb bf16 [m][512].
#define INV512_ 0.001953125f
__global__ __launch_bounds__(1024) void rnn_pass8(
    const float* __restrict__ Xg, const float* __restrict__ Xc,
    const unsigned char* __restrict__ Wgf, const unsigned char* __restrict__ Wcf,
    unsigned short* __restrict__ houtb) {
    __shared__ __align__(16) unsigned char hb8[16 * 520];
    __shared__ __align__(16) unsigned char rhb8[16 * 520];
    __shared__ float hf[2 * 512], uf[2 * 512];
    __shared__ __align__(16) unsigned char wstage[16 * 8192];   // per-wave 2 slots @4KB
    const int tid = threadIdx.x;
    const int w = tid >> 6, lane = tid & 63;   // w in 0..15
    const int arow = lane & 15;
    const int laneoff = lane * 16;
    const int aoffB = arow * 520 + (lane >> 4) * 8;
    const int rb = blockIdx.x * 2;
    const int rot = blockIdx.x & 7;
    unsigned char* wst = wstage + (w << 13);
    const unsigned char* gA = Wgf + ((size_t)(w * 4) * 64) * 16 + laneoff;   // phase A slice
    const unsigned char* gB = Wcf + ((size_t)(w * 2) * 64) * 16 + laneoff;   // phase B slice
    const size_t gsA = 64 * 1024;   // bytes per ktp group, phase A (NT=64)
    const size_t gsB = 32 * 1024;   // phase B (NT=32)

    for (int i = tid; i < 16 * 520; i += 1024) { hb8[i] = 0; rhb8[i] = 0; }
    for (int i = tid; i < 2 * 512; i += 1024) hf[i] = 0.f;
    __syncthreads();

    // prologue: prestage phase-A groups rot, rot+1 into slots 0,1
#pragma unroll
    for (int nt = 0; nt < 4; ++nt)
        gload16(gA + (size_t)rot * gsA + nt * 1024, wst + nt * 1024);
    __builtin_amdgcn_sched_barrier(0);
#pragma unroll
    for (int nt = 0; nt < 4; ++nt)
        gload16(gA + (size_t)((rot + 1) & 7) * gsA + nt * 1024, wst + 4096 + nt * 1024);
    __builtin_amdgcn_sched_barrier(0);

    for (int t = 0; t < T_; ++t) {
        const int m0 = t * 100 + rb, m1 = m0 + 1;
        {   // ---- phase A: gates [N=1024, K=512]; wave w owns n-tiles w*4..w*4+3
            float xg0v[4], xg1v[4];
            f32x4 acc[4];
#pragma unroll
            for (int nt = 0; nt < 4; ++nt) acc[nt] = (f32x4){0.f, 0.f, 0.f, 0.f};
#pragma unroll
            for (int i = 0; i < 8; ++i) {
                const int g = (rot + i) & 7;
                if (i == 3 || i == 4) asm volatile("s_waitcnt vmcnt(12)" ::: "memory");
                else if (i == 7)      asm volatile("s_waitcnt vmcnt(2)" ::: "memory");
                else                  asm volatile("s_waitcnt vmcnt(4)" ::: "memory");
                __builtin_amdgcn_sched_barrier(0);
                unsigned char* lb = wst + (i & 1) * 4096;
                long av0 = *(const long*)(hb8 + aoffB + (2 * g) * 32);
                long av1 = *(const long*)(hb8 + aoffB + (2 * g + 1) * 32);
#pragma unroll
                for (int nt = 0; nt < 4; ++nt) {
                    long2v bv = *(const long2v*)(lb + nt * 1024 + laneoff);
                    acc[nt] = __builtin_amdgcn_mfma_f32_16x16x32_fp8_fp8(av0, bv.x, acc[nt], 0, 0, 0);
                    acc[nt] = __builtin_amdgcn_mfma_f32_16x16x32_fp8_fp8(av1, bv.y, acc[nt], 0, 0, 0);
                }
                __builtin_amdgcn_sched_barrier(0);
                if (i < 6) {            // restage group i+2 into this slot
                    const int g2 = (rot + i + 2) & 7;
#pragma unroll
                    for (int nt = 0; nt < 4; ++nt)
                        gload16(gA + (size_t)g2 * gsA + nt * 1024, lb + nt * 1024);
                } else if (i == 6) {    // prestage phase-B group rot -> B-slot0 (wst+0)
                    gload16(gB + (size_t)rot * gsB, wst);
                    gload16(gB + (size_t)rot * gsB + 1024, wst + 1024);
                } else {                // i==7: prestage phase-B group rot+1 -> B-slot1 (wst+4096)
                    const int gb = (rot + 1) & 7;
                    gload16(gB + (size_t)gb * gsB, wst + 4096);
                    gload16(gB + (size_t)gb * gsB + 1024, wst + 4096 + 1024);
                }
                __builtin_amdgcn_sched_barrier(0);
                if (i == 2) {           // issue Xg loads mid-phase (counted in w3/w4)
                    if (lane < 16) {
#pragma unroll
                        for (int nt = 0; nt < 4; ++nt) {
                            int col = (w * 4 + nt) * 16 + arow;
                            xg0v[nt] = Xg[(size_t)m0 * 1024 + col];
                            xg1v[nt] = Xg[(size_t)m1 * 1024 + col];
                        }
                    }
                    __builtin_amdgcn_sched_barrier(0);
                }
            }
            if (lane < 16) {
#pragma unroll
                for (int nt = 0; nt < 4; ++nt) {
                    int col = (w * 4 + nt) * 16 + arow;
                    float s0 = sigmoidf_(fmaf(acc[nt][0], INV512_, xg0v[nt]));
                    float s1 = sigmoidf_(fmaf(acc[nt][1], INV512_, xg1v[nt]));
                    if (col < 512) {
                        rhb8[col]       = f2e4(16.f * s0 * hf[col]);
                        rhb8[520 + col] = f2e4(16.f * s1 * hf[512 + col]);
                    } else {
                        uf[col - 512] = s0;
                        uf[col]       = s1;
                    }
                }
            }
        }
        asm volatile("s_waitcnt lgkmcnt(0)" ::: "memory");
        __builtin_amdgcn_s_barrier();
        {   // ---- phase B: candidate + h update [N=512, K=512]; n-tiles w*2..w*2+1
            float xc0v[2], xc1v[2];
            f32x4 acc[2];
#pragma unroll
            for (int nt = 0; nt < 2; ++nt) acc[nt] = (f32x4){0.f, 0.f, 0.f, 0.f};
#pragma unroll
            for (int i = 0; i < 8; ++i) {
                const int g = (rot + i) & 7;
                if (i == 3 || i == 4) asm volatile("s_waitcnt vmcnt(6)" ::: "memory");
                else if (i == 7)      asm volatile("s_waitcnt vmcnt(4)" ::: "memory");
                else                  asm volatile("s_waitcnt vmcnt(2)" ::: "memory");
                __builtin_amdgcn_sched_barrier(0);
                unsigned char* lb = wst + (i & 1) * 4096;   // 2KB used per slot
                long av0 = *(const long*)(rhb8 + aoffB + (2 * g) * 32);
                long av1 = *(const long*)(rhb8 + aoffB + (2 * g + 1) * 32);
#pragma unroll
                for (int nt = 0; nt < 2; ++nt) {
                    long2v bv = *(const long2v*)(lb + nt * 1024 + laneoff);
                    acc[nt] = __builtin_amdgcn_mfma_f32_16x16x32_fp8_fp8(av0, bv.x, acc[nt], 0, 0, 0);
                    acc[nt] = __builtin_amdgcn_mfma_f32_16x16x32_fp8_fp8(av1, bv.y, acc[nt], 0, 0, 0);
                }
                __builtin_amdgcn_sched_barrier(0);
                if (i < 6) {            // restage group i+2
                    const int g2 = (rot + i + 2) & 7;
#pragma unroll
                    for (int nt = 0; nt < 2; ++nt)
                        gload16(gB + (size_t)g2 * gsB + nt * 1024, lb + nt * 1024);
                } else if (i == 6) {    // prestage next-step phase-A group rot -> A-slot0
#pragma unroll
                    for (int nt = 0; nt < 4; ++nt)
                        gload16(gA + (size_t)rot * gsA + nt * 1024, wst + nt * 1024);
                } else {                // i==7: prestage phase-A group rot+1 -> A-slot1
                    const int ga1 = (rot + 1) & 7;
#pragma unroll
                    for (int nt = 0; nt < 4; ++nt)
                        gload16(gA + (size_t)ga1 * gsA + nt * 1024, wst + 4096 + nt * 1024);
                }
                __builtin_amdgcn_sched_barrier(0);
                if (i == 2) {
                    if (lane < 16) {
#pragma unroll
                        for (int nt = 0; nt < 2; ++nt) {
                            int col = (w * 2 + nt) * 16 + arow;
                            xc0v[nt] = Xc[(size_t)m0 * 512 + col];
                            xc1v[nt] = Xc[(size_t)m1 * 512 + col];
                        }
                    }
                    __builtin_amdgcn_sched_barrier(0);
                }
            }
            if (lane < 16) {
#pragma unroll
                for (int nt = 0; nt < 2; ++nt) {
                    int col = (w * 2 + nt) * 16 + arow;
                    float c0 = tanhf(fmaf(acc[nt][0], INV512_, xc0v[nt]));
                    float c1 = tanhf(fmaf(acc[nt][1], INV512_, xc1v[nt]));
                    float uA = uf[col], uB = uf[512 + col];
                    float hA = uA * hf[col] + (1.f - uA) * c0;
                    float hB = uB * hf[512 + col] + (1.f - uB) * c1;
                    hf[col] = hA; hf[512 + col] = hB;
                    hb8[col] = f2e4(16.f * hA); hb8[520 + col] = f2e4(16.f * hB);
                    houtb[(size_t)m0 * 512 + col] = f2b(hA);
                    houtb[(size_t)m1 * 512 + col] = f2b(hB);
                }
            }
        }
        asm volatile("s_waitcnt lgkmcnt(0)" ::: "memory");
        __builtin_amdgcn_s_barrier();
    }
}

// ---------------- batched MFMA x-projection GEMM: C[M][N] = Abf[M][LDA] @ Wf + bias
template<int NTW, int KT, int LDA>
__global__ __launch_bounds__(256) void xproj_mfma(const unsigned short* __restrict__ Abf,
                                                  const unsigned short* __restrict__ Wf,
                                                  const float* __restrict__ bias,
                                                  float* __restrict__ C, int M) {
    const int NT = NTW * 4;
    const int N = NT * 16;
    const int tid = threadIdx.x;
    const int w = tid >> 6, lane = tid & 63;
    const int arow = lane & 15, hi = lane >> 4;
    const int mbase = blockIdx.x * 16;
    int ga = mbase + arow; if (ga >= M) ga = M - 1;      // clamp reads; stores guarded
    const unsigned short* ap = Abf + (size_t)ga * LDA + hi * 8;
    f32x4 acc[NTW];
#pragma unroll
    for (int nt = 0; nt < NTW; ++nt) acc[nt] = (f32x4){0.f, 0.f, 0.f, 0.f};
#pragma unroll 2
    for (int kt = 0; kt < KT; ++kt) {
        short8v af = *(const short8v*)(ap + kt * 32);
        const unsigned short* wp = Wf + ((size_t)(kt * NT + w * NTW) * 64 + lane) * 8;
#pragma unroll
        for (int nt = 0; nt < NTW; ++nt) {
            short8v bf = *(const short8v*)(wp + (size_t)nt * 512);
            acc[nt] = __builtin_amdgcn_mfma_f32_16x16x32_bf16(af, bf, acc[nt], 0, 0, 0);
        }
    }
#pragma unroll
    for (int nt = 0; nt < NTW; ++nt) {
        int col = (w * NTW + nt) * 16 + arow;
        float bb = bias[col];
#pragma unroll
        for (int q = 0; q < 4; ++q) {
            int gm = mbase + hi * 4 + q;
            if (gm < M) C[(size_t)gm * N + col] = acc[nt][q] + bb;
        }
    }
}

// ---------------- MFMA fused softmax GEMM + LSE partials + target pick
__global__ __launch_bounds__(256) void lse_mfma(const unsigned short* __restrict__ Abf,
                                                const unsigned short* __restrict__ swf,
                                                const float* __restrict__ sb,
                                                const int* __restrict__ tgt,
                                                float* __restrict__ zt,
                                                float* __restrict__ parts) {
    const int tid = threadIdx.x;
    const int w = tid >> 6, lane = tid & 63;
    const int arow = lane & 15, hi = lane >> 4;
    const int mbase = blockIdx.y * 64 + w * 16;          // wave-private 16-row M-tile
    const int ntg0 = blockIdx.x * 4;                     // 4 n-tiles = 64 cols
    int ga = mbase + arow; if (ga >= BT_) ga = BT_ - 1;  // clamp reads
    const unsigned short* ap = Abf + (size_t)ga * 512 + hi * 8;
    f32x4 acc[4];
#pragma unroll
    for (int nt = 0; nt < 4; ++nt) acc[nt] = (f32x4){0.f, 0.f, 0.f, 0.f};
#pragma unroll 2
    for (int kt = 0; kt < 16; ++kt) {
        short8v af = *(const short8v*)(ap + kt * 32);
        const unsigned short* wp = swf + ((size_t)(kt * 500 + ntg0) * 64 + lane) * 8;
#pragma unroll
        for (int nt = 0; nt < 4; ++nt) {
            short8v bf = *(const short8v*)(wp + (size_t)nt * 512);
            acc[nt] = __builtin_amdgcn_mfma_f32_16x16x32_bf16(af, bf, acc[nt], 0, 0, 0);
        }
    }
#pragma unroll
    for (int nt = 0; nt < 4; ++nt) {
        float bb = sb[(ntg0 + nt) * 16 + arow];
#pragma unroll
        for (int q = 0; q < 4; ++q) acc[nt][q] += bb;
    }
#pragma unroll
    for (int q = 0; q < 4; ++q) {
        int gr = mbase + hi * 4 + q;
        if (gr < BT_) {
            int tg = tgt[(gr % 100) * 50 + gr / 100];
            int lt = tg - arow;
#pragma unroll
            for (int nt = 0; nt < 4; ++nt)
                if (lt == (ntg0 + nt) * 16) zt[gr] = acc[nt][q];
        }
    }
    float lm[4], ls[4];
#pragma unroll
    for (int q = 0; q < 4; ++q)
        lm[q] = fmaxf(fmaxf(acc[0][q], acc[1][q]), fmaxf(acc[2][q], acc[3][q]));
#pragma unroll
    for (int mask = 1; mask < 16; mask <<= 1)
#pragma unroll
        for (int q = 0; q < 4; ++q) lm[q] = fmaxf(lm[q], __shfl_xor(lm[q], mask));
#pragma unroll
    for (int q = 0; q < 4; ++q) {
        float s = 0.f;
#pragma unroll
        for (int nt = 0; nt < 4; ++nt) s += expf(acc[nt][q] - lm[q]);
        ls[q] = s;
    }
#pragma unroll
    for (int mask = 1; mask < 16; mask <<= 1)
#pragma unroll
        for (int q = 0; q < 4; ++q) ls[q] += __shfl_xor(ls[q], mask);
    if (arow == 0) {
#pragma unroll
        for (int q = 0; q < 4; ++q) {
            int gr = mbase + hi * 4 + q;
            if (gr < BT_) {
                parts[(size_t)gr * 250 + blockIdx.x * 2 + 0] = lm[q];
                parts[(size_t)gr * 250 + blockIdx.x * 2 + 1] = ls[q];
            }
        }
    }
}

// ---------------- merge partials -> NLL -> block sums
__global__ __launch_bounds__(128) void final_nll(const float* __restrict__ parts,
                                                 const float* __restrict__ zt,
                                                 float* __restrict__ bsum) {
    int i = blockIdx.x * 128 + threadIdx.x;
    float nll = 0.f;
    if (i < BT_) {
        const float* p = parts + (size_t)i * 250;
        float M = p[0];
        for (int j = 1; j < 125; ++j) M = fmaxf(M, p[2 * j]);
        float S = 0.f;
        for (int j = 0; j < 125; ++j) S += p[2 * j + 1] * expf(p[2 * j] - M);
        nll = M + logf(S) - zt[i];
    }
    __shared__ float red[128];
    red[threadIdx.x] = nll;
    __syncthreads();
    for (int s = 64; s > 0; s >>= 1) {
        if (threadIdx.x < s) red[threadIdx.x] += red[threadIdx.x + s];
        __syncthreads();
    }
    if (threadIdx.x == 0) bsum[blockIdx.x] = red[0];
}

__global__ __launch_bounds__(64) void final_sum(const float* __restrict__ bsum,
                                                float* __restrict__ out) {
    int tid = threadIdx.x;
    float v = (tid < 40) ? bsum[tid] : 0.f;
    for (int off = 32; off > 0; off >>= 1) v += __shfl_down(v, off);
    if (tid == 0) out[0] = v / 5000.0f;
}

extern "C" void kernel_launch(void* const* d_in, const int* in_sizes, int n_in,
                              void* d_out, int out_size, void* d_ws, size_t ws_size,
                              hipStream_t stream) {
    const int*   inp   = (const int*)d_in[0];
    const int*   langs = (const int*)d_in[1];
    const int*   tgt   = (const int*)d_in[2];
    const float* emb   = (const float*)d_in[3];
    const float* lemb  = (const float*)d_in[4];
    const float* Wg0   = (const float*)d_in[5];
    const float* bg0   = (const float*)d_in[6];
    const float* Wc0   = (const float*)d_in[7];
    const float* bc0   = (const float*)d_in[8];
    const float* Wg1   = (const float*)d_in[9];
    const float* bg1   = (const float*)d_in[10];
    const float* Wc1   = (const float*)d_in[11];
    const float* bc1   = (const float*)d_in[12];
    const float* sw    = (const float*)d_in[13];
    const float* sb    = (const float*)d_in[14];
    float* out = (float*)d_out;

    // workspace layout (floats), max offset ~11.19M floats = 44.8 MB
    float* w = (float*)d_ws;
    // region A [0 .. 1,200,000 fl): nemb, later aliased by packed recurrent/x1 frags
    float* nemb = w;
    unsigned char* a8 = (unsigned char*)w;
    unsigned char* Wg0f8  = a8;                          //   524,288 B (fp8, paired kt)
    unsigned char* Wc0f8  = a8 + 524288;                 //   262,144 B
    unsigned char* Wg1hf8 = a8 + 786432;                 //   524,288 B
    unsigned char* Wc1hf8 = a8 + 1310720;                //   262,144 B (ends 1,572,864 B)
    unsigned short* Wg1xf = (unsigned short*)(a8 + 1572864);   // 524,288 u16
    unsigned short* Wc1xf = Wg1xf + 524288;                    // 262,144 u16 (ends 3,145,728 B)
    float* nlang = w + 1200000;             // 512
    // xsb bf16 [5000][224] @1,200,512 (560,000 fl), then layer-0 x-side bf16 frags
    unsigned short* xsb   = (unsigned short*)(w + 1200512);    // 1,120,000 u16
    unsigned short* Wg0xf = (unsigned short*)(w + 1760512);    //   229,376 u16 (114,688 fl)
    unsigned short* Wc0xf = (unsigned short*)(w + 1875200);    //   114,688 u16 ( 57,344 fl)
    // region B @2200512 (5.12M fl): Xg0 -> Xg1 (alias) -> swf (alias, after pass2)
    float* Xg0   = w + 2200512;
    float* Xg1   = w + 2200512;
    unsigned short* swf = (unsigned short*)(w + 2200512);      // 8,192,000 u16
    // region C @7320512 (2.56M fl): Xc0 -> Xc1 (alias) -> parts/zt/bsum (alias)
    float* Xc0   = w + 7320512;
    float* Xc1   = w + 7320512;
    float* parts = w + 7320512;             // 1,250,000
    float* ztb   = w + 7320512 + 1250000;   // 5,000
    float* bsum  = w + 7320512 + 1255000;   // 64
    // region D @9880512: h0seq bf16 -> h1o bf16 (alias)
    unsigned short* h0seq = (unsigned short*)(w + 9880512);    // 2,621,440 u16
    unsigned short* h1o   = (unsigned short*)(w + 9880512);    // 2,560,000 u16

    norm_rows<<<V_, 256, 0, stream>>>(emb, nemb, V_, E_);
    norm_rows<<<10, 256, 0, stream>>>(lemb, nlang, 10, LD_);
    build_xsb<<<(BT_ * KXP_ + 255) / 256, 256, 0, stream>>>(inp, langs, nemb, nlang, xsb);
    // pack recurrent weight slices to fp8 (scale 32); x-side & lse to bf16 (over dead nemb)
    pack_frags8<<<256, 256, 0, stream>>>(Wg0, 1024, D0_, 16, 64, Wg0f8, 32.f);
    pack_frags8<<<128, 256, 0, stream>>>(Wc0,  512, D0_, 16, 32, Wc0f8, 32.f);
    pack_frags8<<<256, 256, 0, stream>>>(Wg1, 1024, 512, 16, 64, Wg1hf8, 32.f);
    pack_frags8<<<128, 256, 0, stream>>>(Wc1,  512, 512, 16, 32, Wc1hf8, 32.f);
    pack_frags<<<256, 256, 0, stream>>>(Wg1, 1024, 0, 16, 64, Wg1xf, 1 << 30);
    pack_frags<<<128, 256, 0, stream>>>(Wc1,  512, 0, 16, 32, Wc1xf, 1 << 30);
    pack_frags<<<112, 256, 0, stream>>>(Wg0, 1024, 0, 7, 64, Wg0xf, D0_);   // x-part, K=224 pad
    pack_frags<<<56, 256, 0, stream>>>(Wc0,  512, 0, 7, 32, Wc0xf, D0_);
    // layer-0 input projections (bf16 MFMA, K=224)
    xproj_mfma<16, 7, KXP_><<<313, 256, 0, stream>>>(xsb, Wg0xf, bg0, Xg0, BT_);
    xproj_mfma<8, 7, KXP_><<<313, 256, 0, stream>>>(xsb, Wc0xf, bc0, Xc0, BT_);
    // pass 1: layer-0 recurrence (fp8, ring-2 + cross-phase prestage) -> h0seq (bf16)
    rnn_pass8<<<50, 1024, 0, stream>>>(Xg0, Xc0, Wg0f8, Wc0f8, h0seq);
    // layer-1 input projections from h0seq (bf16 MFMA, K=512)
    xproj_mfma<16, 16, 512><<<313, 256, 0, stream>>>(h0seq, Wg1xf, bg1, Xg1, BT_);
    xproj_mfma<8, 16, 512><<<313, 256, 0, stream>>>(h0seq, Wc1xf, bc1, Xc1, BT_);
    // pass 2: layer-1 recurrence (fp8, ring-2 + cross-phase prestage) -> h1o (bf16)
    rnn_pass8<<<50, 1024, 0, stream>>>(Xg1, Xc1, Wg1hf8, Wc1hf8, h1o);
    // pack softmax weights to bf16 frags (over dead Xg1)
    pack_frags<<<2000, 256, 0, stream>>>(sw, NV_, 0, 16, 500, swf, 1 << 30);
    // fused MFMA softmax GEMM + LSE partials + target pick (parts over dead Xc1)
    lse_mfma<<<dim3(125, 79), 256, 0, stream>>>(h1o, swf, sb, tgt, ztb, parts);
    final_nll<<<40, 128, 0, stream>>>(parts, ztb, bsum);
    final_sum<<<1, 64, 0, stream>>>(bsum, out);
}

// Round 14
// 1540.624 us; speedup vs baseline: 1.0878x; 1.0695x over previous
//
#include <hip/hip_runtime.h>
#include <hip/hip_bf16.h>
#include <hip/hip_fp8.h>
#include <math.h>

// Problem constants
#define V_    8000
#define E_    150
#define LD_   50
#define H_    512
#define B_    100
#define T_    50
#define D0_   200   // E_+LD_
#define BT_   5000  // B_*T_
#define NV_   8000
#define KXP_  224   // padded layer-0 input K (200 -> 224)

typedef __attribute__((ext_vector_type(8))) short short8v;
typedef __attribute__((ext_vector_type(4))) float f32x4;
typedef __attribute__((ext_vector_type(2))) long long2v;

__device__ __forceinline__ float sigmoidf_(float x) { return 1.0f / (1.0f + expf(-x)); }
__device__ __forceinline__ unsigned short f2b(float x) {
    __hip_bfloat16 b = __float2bfloat16(x);
    return *(unsigned short*)&b;
}
__device__ __forceinline__ unsigned char f2e4(float x) {
    __hip_fp8_e4m3 v(x);           // OCP e4m3fn
    return (unsigned char)v.__x;
}
// async global->LDS: 64 lanes x 16B, lds dest = uniform base + lane*16
__device__ __forceinline__ void gload16(const void* g, void* l) {
    __builtin_amdgcn_global_load_lds(
        (__attribute__((address_space(1))) void*)(g),
        (__attribute__((address_space(3))) void*)(l), 16, 0, 0);
}

// ---------------- fused row L2-normalize for emb (8000 rows) + lang_emb (10 rows)
__global__ __launch_bounds__(256) void norm_both(const float* __restrict__ emb,
                                                 const float* __restrict__ lemb,
                                                 float* __restrict__ nemb,
                                                 float* __restrict__ nlang) {
    int b = blockIdx.x;
    const float* in; float* out; int row, C;
    if (b < V_) { in = emb; out = nemb; row = b; C = E_; }
    else        { in = lemb; out = nlang; row = b - V_; C = LD_; }
    int tid = threadIdx.x;
    float v = (tid < C) ? in[(size_t)row * C + tid] : 0.f;
    __shared__ float red[256];
    red[tid] = v * v;
    __syncthreads();
    for (int s = 128; s > 0; s >>= 1) {
        if (tid < s) red[tid] += red[tid + s];
        __syncthreads();
    }
    float scale = rsqrtf(fmaxf(red[0], 1e-12f));
    if (tid < C) out[(size_t)row * C + tid] = v * scale;
}

// ---------------- build xsb bf16 [m=t*100+b][KXP_], cols >=200 zero
__global__ void build_xsb(const int* __restrict__ inp, const int* __restrict__ langs,
                          const float* __restrict__ nemb, const float* __restrict__ nlang,
                          unsigned short* __restrict__ xsb) {
    int idx = blockIdx.x * 256 + threadIdx.x;
    if (idx >= BT_ * KXP_) return;
    int m = idx / KXP_, e = idx % KXP_;
    int b = m % 100, t = m / 100;
    float v = 0.f;
    if (e < E_)       v = nemb[(size_t)inp[b * T_ + t] * E_ + e];
    else if (e < D0_) v = nlang[(size_t)langs[b] * LD_ + (e - E_)];
    xsb[idx] = f2b(v);
}

// ---------------- device pack helpers
__device__ __forceinline__ void pack_b16_dev(const float* __restrict__ W, int ldw,
                                             int k0off, int NT, int klim,
                                             unsigned short* __restrict__ dst, int idx) {
    int lane = idx & 63;
    int tile = idx >> 6;
    int nt = tile % NT, kt = tile / NT;
    int n = nt * 16 + (lane & 15);
    int kb = k0off + kt * 32 + (lane >> 4) * 8;
    unsigned short o[8];
#pragma unroll
    for (int j = 0; j < 8; ++j)
        o[j] = (kb + j < klim) ? f2b(W[(size_t)(kb + j) * ldw + n]) : 0;
    *(uint4*)(dst + (size_t)idx * 8) = *(const uint4*)o;
}
__device__ __forceinline__ void pack_f8_dev(const float* __restrict__ W, int ldw,
                                            int k0off, int NT,
                                            unsigned char* __restrict__ dst, int idx) {
    int lane = idx & 63;
    int tile = idx >> 6;
    int nt = tile % NT, kt = tile / NT;
    int n = nt * 16 + (lane & 15);
    int kb = k0off + kt * 32 + (lane >> 4) * 8;
    unsigned char o[8];
#pragma unroll
    for (int j = 0; j < 8; ++j) o[j] = f2e4(W[(size_t)(kb + j) * ldw + n] * 32.f);
    size_t off = ((((size_t)(kt >> 1) * NT + nt) * 64 + lane) << 4) + ((kt & 1) << 3);
    *(unsigned long long*)(dst + off) = *(const unsigned long long*)o;
}

// ---------------- one dispatcher kernel for all 8 weight packs (saves 7 launches)
__global__ __launch_bounds__(256) void pack_all(
    const float* __restrict__ Wg0, const float* __restrict__ Wc0,
    const float* __restrict__ Wg1, const float* __restrict__ Wc1,
    unsigned char* __restrict__ Wg0f8, unsigned char* __restrict__ Wc0f8,
    unsigned char* __restrict__ Wg1hf8, unsigned char* __restrict__ Wc1hf8,
    unsigned short* __restrict__ Wg1xf, unsigned short* __restrict__ Wc1xf,
    unsigned short* __restrict__ Wg0xf, unsigned short* __restrict__ Wc0xf) {
    int b = blockIdx.x, tid = threadIdx.x;
    if (b < 256)        pack_f8_dev(Wg0, 1024, D0_, 64, Wg0f8, b * 256 + tid);
    else if (b < 384)   pack_f8_dev(Wc0,  512, D0_, 32, Wc0f8, (b - 256) * 256 + tid);
    else if (b < 640)   pack_f8_dev(Wg1, 1024, 512, 64, Wg1hf8, (b - 384) * 256 + tid);
    else if (b < 768)   pack_f8_dev(Wc1,  512, 512, 32, Wc1hf8, (b - 640) * 256 + tid);
    else if (b < 1024)  pack_b16_dev(Wg1, 1024, 0, 64, 1 << 30, Wg1xf, (b - 768) * 256 + tid);
    else if (b < 1152)  pack_b16_dev(Wc1,  512, 0, 32, 1 << 30, Wc1xf, (b - 1024) * 256 + tid);
    else if (b < 1264)  pack_b16_dev(Wg0, 1024, 0, 64, D0_, Wg0xf, (b - 1152) * 256 + tid);
    else                pack_b16_dev(Wc0,  512, 0, 32, D0_, Wc0xf, (b - 1264) * 256 + tid);
}

// ---------------- pack fp32 weight into bf16 MFMA B-frag layout (for swf)
__global__ __launch_bounds__(256) void pack_frags(const float* __restrict__ W, int ldw,
                                                  int KT, int NT,
                                                  unsigned short* __restrict__ dst) {
    int idx = blockIdx.x * 256 + threadIdx.x;
    if (idx >= KT * NT * 64) return;
    pack_b16_dev(W, ldw, 0, NT, 1 << 30, dst, idx);
}

// ---------------- fp8 MFMA phase with wave-private LDS staging + counted vmcnt.
// (round-11 proven schedule: ring-2 of 4KB groups, vmcnt(NTW) mid-loop, vmcnt(0) tail)
// gsrc0 = per-lane global base of this wave's n-slice (includes lane*16).
// wst = this wave's private LDS region (2 bufs x NTW KB). K = 512 (8 ktp groups).
template<int NTW>
__device__ __forceinline__ void mm_phase8s(const unsigned char* gsrc0, int NT,
                                           const unsigned char* a0, unsigned char* wst,
                                           int laneoff, int aoffB, f32x4* acc) {
    const size_t gstride = (size_t)NT * 1024;     // bytes per ktp group (whole block)
    // prologue: stage groups 0,1 into buf0,buf1
#pragma unroll
    for (int nt = 0; nt < NTW; ++nt) gload16(gsrc0 + nt * 1024, wst + nt * 1024);
    __builtin_amdgcn_sched_barrier(0);
#pragma unroll
    for (int nt = 0; nt < NTW; ++nt)
        gload16(gsrc0 + gstride + nt * 1024, wst + (NTW + nt) * 1024);
    __builtin_amdgcn_sched_barrier(0);
#pragma unroll
    for (int ktp = 0; ktp < 8; ++ktp) {
        // wait for group ktp (allow the NTW loads of group ktp+1 to stay in flight)
        if (ktp < 7) {
            if (NTW == 4) asm volatile("s_waitcnt vmcnt(4)" ::: "memory");
            else          asm volatile("s_waitcnt vmcnt(2)" ::: "memory");
        } else {
            asm volatile("s_waitcnt vmcnt(0)" ::: "memory");
        }
        __builtin_amdgcn_sched_barrier(0);
        unsigned char* lb = wst + (ktp & 1) * (NTW * 1024);
        long av0 = *(const long*)(a0 + aoffB + (2 * ktp) * 32);
        long av1 = *(const long*)(a0 + aoffB + (2 * ktp + 1) * 32);
#pragma unroll
        for (int nt = 0; nt < NTW; ++nt) {
            long2v bv = *(const long2v*)(lb + nt * 1024 + laneoff);
            acc[nt] = __builtin_amdgcn_mfma_f32_16x16x32_fp8_fp8(av0, bv.x, acc[nt], 0, 0, 0);
            acc[nt] = __builtin_amdgcn_mfma_f32_16x16x32_fp8_fp8(av1, bv.y, acc[nt], 0, 0, 0);
        }
        __builtin_amdgcn_sched_barrier(0);
        // restage buf just consumed with group ktp+2
        if (ktp + 2 < 8) {
#pragma unroll
            for (int nt = 0; nt < NTW; ++nt)
                gload16(gsrc0 + (size_t)(ktp + 2) * gstride + nt * 1024, lb + nt * 1024);
            __builtin_amdgcn_sched_barrier(0);
        }
    }
}

// ---------------- one-layer GRU pass (fp8 weights, LDS-staged, fp32 master state):
// 50 blocks x 2 batch rows, 1024 threads (16 waves). Weights 0.75 MB/step (L2-resident).
// acc = (16h)@(32W) = 512*(h@W) -> epilogue scales by 1/512. Output houtb bf16 [m][512].
#define INV512_ 0.001953125f
__global__ __launch_bounds__(1024) void rnn_pass8(
    const float* __restrict__ Xg, const float* __restrict__ Xc,
    const unsigned char* __restrict__ Wgf, const unsigned char* __restrict__ Wcf,
    unsigned short* __restrict__ houtb) {
    __shared__ __align__(16) unsigned char hb8[16 * 520];
    __shared__ __align__(16) unsigned char rhb8[16 * 520];
    __shared__ float hf[2 * 512], uf[2 * 512];
    __shared__ __align__(16) unsigned char wstage[16 * 8192];   // 128KB: per-wave 2x4KB bufs
    const int tid = threadIdx.x;
    const int w = tid >> 6, lane = tid & 63;   // w in 0..15
    const int arow = lane & 15;
    const int laneoff = lane * 16;
    const int aoffB = arow * 520 + (lane >> 4) * 8;
    const int rb = blockIdx.x * 2;
    unsigned char* wst = wstage + (w << 13);
    const unsigned char* gA = Wgf + ((size_t)(w * 4) * 64) * 16 + laneoff;   // phase A slice
    const unsigned char* gB = Wcf + ((size_t)(w * 2) * 64) * 16 + laneoff;   // phase B slice

    for (int i = tid; i < 16 * 520; i += 1024) { hb8[i] = 0; rhb8[i] = 0; }
    for (int i = tid; i < 2 * 512; i += 1024) hf[i] = 0.f;
    __syncthreads();

    for (int t = 0; t < T_; ++t) {
        const int m0 = t * 100 + rb, m1 = m0 + 1;
        {   // phase A: gates [N=1024, K=512]; wave w owns n-tiles w*4..w*4+3
            float xg0v[4], xg1v[4];
            if (lane < 16) {   // issue Xg loads first (oldest -> retired by first wait)
#pragma unroll
                for (int nt = 0; nt < 4; ++nt) {
                    int col = (w * 4 + nt) * 16 + arow;
                    xg0v[nt] = Xg[(size_t)m0 * 1024 + col];
                    xg1v[nt] = Xg[(size_t)m1 * 1024 + col];
                }
            }
            __builtin_amdgcn_sched_barrier(0);
            f32x4 acc[4];
#pragma unroll
            for (int nt = 0; nt < 4; ++nt) acc[nt] = (f32x4){0.f, 0.f, 0.f, 0.f};
            mm_phase8s<4>(gA, 64, hb8, wst, laneoff, aoffB, acc);
            if (lane < 16) {
#pragma unroll
                for (int nt = 0; nt < 4; ++nt) {
                    int col = (w * 4 + nt) * 16 + arow;
                    float s0 = sigmoidf_(fmaf(acc[nt][0], INV512_, xg0v[nt]));
                    float s1 = sigmoidf_(fmaf(acc[nt][1], INV512_, xg1v[nt]));
                    if (col < 512) {
                        rhb8[col]       = f2e4(16.f * s0 * hf[col]);
                        rhb8[520 + col] = f2e4(16.f * s1 * hf[512 + col]);
                    } else {
                        uf[col - 512] = s0;
                        uf[col]       = s1;
                    }
                }
            }
        }
        __syncthreads();
        {   // phase B: candidate + h update [N=512, K=512]; wave w owns n-tiles w*2..w*2+1
            float xc0v[2], xc1v[2];
            if (lane < 16) {
#pragma unroll
                for (int nt = 0; nt < 2; ++nt) {
                    int col = (w * 2 + nt) * 16 + arow;
                    xc0v[nt] = Xc[(size_t)m0 * 512 + col];
                    xc1v[nt] = Xc[(size_t)m1 * 512 + col];
                }
            }
            __builtin_amdgcn_sched_barrier(0);
            f32x4 acc[2];
#pragma unroll
            for (int nt = 0; nt < 2; ++nt) acc[nt] = (f32x4){0.f, 0.f, 0.f, 0.f};
            mm_phase8s<2>(gB, 32, rhb8, wst, laneoff, aoffB, acc);
            if (lane < 16) {
#pragma unroll
                for (int nt = 0; nt < 2; ++nt) {
                    int col = (w * 2 + nt) * 16 + arow;
                    float c0 = tanhf(fmaf(acc[nt][0], INV512_, xc0v[nt]));
                    float c1 = tanhf(fmaf(acc[nt][1], INV512_, xc1v[nt]));
                    float uA = uf[col], uB = uf[512 + col];
                    float hA = uA * hf[col] + (1.f - uA) * c0;
                    float hB = uB * hf[512 + col] + (1.f - uB) * c1;
                    hf[col] = hA; hf[512 + col] = hB;
                    hb8[col] = f2e4(16.f * hA); hb8[520 + col] = f2e4(16.f * hB);
                    houtb[(size_t)m0 * 512 + col] = f2b(hA);
                    houtb[(size_t)m1 * 512 + col] = f2b(hB);
                }
            }
        }
        __syncthreads();
    }
}

// ---------------- batched MFMA x-projection GEMM: C[M][N] = Abf[M][LDA] @ Wf + bias
template<int NTW, int KT, int LDA>
__global__ __launch_bounds__(256) void xproj_mfma(const unsigned short* __restrict__ Abf,
                                                  const unsigned short* __restrict__ Wf,
                                                  const float* __restrict__ bias,
                                                  float* __restrict__ C, int M) {
    const int NT = NTW * 4;
    const int N = NT * 16;
    const int tid = threadIdx.x;
    const int w = tid >> 6, lane = tid & 63;
    const int arow = lane & 15, hi = lane >> 4;
    const int mbase = blockIdx.x * 16;
    int ga = mbase + arow; if (ga >= M) ga = M - 1;      // clamp reads; stores guarded
    const unsigned short* ap = Abf + (size_t)ga * LDA + hi * 8;
    f32x4 acc[NTW];
#pragma unroll
    for (int nt = 0; nt < NTW; ++nt) acc[nt] = (f32x4){0.f, 0.f, 0.f, 0.f};
#pragma unroll 2
    for (int kt = 0; kt < KT; ++kt) {
        short8v af = *(const short8v*)(ap + kt * 32);
        const unsigned short* wp = Wf + ((size_t)(kt * NT + w * NTW) * 64 + lane) * 8;
#pragma unroll
        for (int nt = 0; nt < NTW; ++nt) {
            short8v bf = *(const short8v*)(wp + (size_t)nt * 512);
            acc[nt] = __builtin_amdgcn_mfma_f32_16x16x32_bf16(af, bf, acc[nt], 0, 0, 0);
        }
    }
#pragma unroll
    for (int nt = 0; nt < NTW; ++nt) {
        int col = (w * NTW + nt) * 16 + arow;
        float bb = bias[col];
#pragma unroll
        for (int q = 0; q < 4; ++q) {
            int gm = mbase + hi * 4 + q;
            if (gm < M) C[(size_t)gm * N + col] = acc[nt][q] + bb;
        }
    }
}

// ---------------- MFMA fused softmax GEMM + LSE partials + target pick
__global__ __launch_bounds__(256) void lse_mfma(const unsigned short* __restrict__ Abf,
                                                const unsigned short* __restrict__ swf,
                                                const float* __restrict__ sb,
                                                const int* __restrict__ tgt,
                                                float* __restrict__ zt,
                                                float* __restrict__ parts) {
    const int tid = threadIdx.x;
    const int w = tid >> 6, lane = tid & 63;
    const int arow = lane & 15, hi = lane >> 4;
    const int mbase = blockIdx.y * 64 + w * 16;          // wave-private 16-row M-tile
    const int ntg0 = blockIdx.x * 4;                     // 4 n-tiles = 64 cols
    int ga = mbase + arow; if (ga >= BT_) ga = BT_ - 1;  // clamp reads
    const unsigned short* ap = Abf + (size_t)ga * 512 + hi * 8;
    f32x4 acc[4];
#pragma unroll
    for (int nt = 0; nt < 4; ++nt) acc[nt] = (f32x4){0.f, 0.f, 0.f, 0.f};
#pragma unroll 2
    for (int kt = 0; kt < 16; ++kt) {
        short8v af = *(const short8v*)(ap + kt * 32);
        const unsigned short* wp = swf + ((size_t)(kt * 500 + ntg0) * 64 + lane) * 8;
#pragma unroll
        for (int nt = 0; nt < 4; ++nt) {
            short8v bf = *(const short8v*)(wp + (size_t)nt * 512);
            acc[nt] = __builtin_amdgcn_mfma_f32_16x16x32_bf16(af, bf, acc[nt], 0, 0, 0);
        }
    }
#pragma unroll
    for (int nt = 0; nt < 4; ++nt) {
        float bb = sb[(ntg0 + nt) * 16 + arow];
#pragma unroll
        for (int q = 0; q < 4; ++q) acc[nt][q] += bb;
    }
#pragma unroll
    for (int q = 0; q < 4; ++q) {
        int gr = mbase + hi * 4 + q;
        if (gr < BT_) {
            int tg = tgt[(gr % 100) * 50 + gr / 100];
            int lt = tg - arow;
#pragma unroll
            for (int nt = 0; nt < 4; ++nt)
                if (lt == (ntg0 + nt) * 16) zt[gr] = acc[nt][q];
        }
    }
    float lm[4], ls[4];
#pragma unroll
    for (int q = 0; q < 4; ++q)
        lm[q] = fmaxf(fmaxf(acc[0][q], acc[1][q]), fmaxf(acc[2][q], acc[3][q]));
#pragma unroll
    for (int mask = 1; mask < 16; mask <<= 1)
#pragma unroll
        for (int q = 0; q < 4; ++q) lm[q] = fmaxf(lm[q], __shfl_xor(lm[q], mask));
#pragma unroll
    for (int q = 0; q < 4; ++q) {
        float s = 0.f;
#pragma unroll
        for (int nt = 0; nt < 4; ++nt) s += expf(acc[nt][q] - lm[q]);
        ls[q] = s;
    }
#pragma unroll
    for (int mask = 1; mask < 16; mask <<= 1)
#pragma unroll
        for (int q = 0; q < 4; ++q) ls[q] += __shfl_xor(ls[q], mask);
    if (arow == 0) {
#pragma unroll
        for (int q = 0; q < 4; ++q) {
            int gr = mbase + hi * 4 + q;
            if (gr < BT_) {
                parts[(size_t)gr * 250 + blockIdx.x * 2 + 0] = lm[q];
                parts[(size_t)gr * 250 + blockIdx.x * 2 + 1] = ls[q];
            }
        }
    }
}

// ---------------- merge partials -> NLL -> block sums
__global__ __launch_bounds__(128) void final_nll(const float* __restrict__ parts,
                                                 const float* __restrict__ zt,
                                                 float* __restrict__ bsum) {
    int i = blockIdx.x * 128 + threadIdx.x;
    float nll = 0.f;
    if (i < BT_) {
        const float* p = parts + (size_t)i * 250;
        float M = p[0];
        for (int j = 1; j < 125; ++j) M = fmaxf(M, p[2 * j]);
        float S = 0.f;
        for (int j = 0; j < 125; ++j) S += p[2 * j + 1] * expf(p[2 * j] - M);
        nll = M + logf(S) - zt[i];
    }
    __shared__ float red[128];
    red[threadIdx.x] = nll;
    __syncthreads();
    for (int s = 64; s > 0; s >>= 1) {
        if (threadIdx.x < s) red[threadIdx.x] += red[threadIdx.x + s];
        __syncthreads();
    }
    if (threadIdx.x == 0) bsum[blockIdx.x] = red[0];
}

__global__ __launch_bounds__(64) void final_sum(const float* __restrict__ bsum,
                                                float* __restrict__ out) {
    int tid = threadIdx.x;
    float v = (tid < 40) ? bsum[tid] : 0.f;
    for (int off = 32; off > 0; off >>= 1) v += __shfl_down(v, off);
    if (tid == 0) out[0] = v / 5000.0f;
}

extern "C" void kernel_launch(void* const* d_in, const int* in_sizes, int n_in,
                              void* d_out, int out_size, void* d_ws, size_t ws_size,
                              hipStream_t stream) {
    const int*   inp   = (const int*)d_in[0];
    const int*   langs = (const int*)d_in[1];
    const int*   tgt   = (const int*)d_in[2];
    const float* emb   = (const float*)d_in[3];
    const float* lemb  = (const float*)d_in[4];
    const float* Wg0   = (const float*)d_in[5];
    const float* bg0   = (const float*)d_in[6];
    const float* Wc0   = (const float*)d_in[7];
    const float* bc0   = (const float*)d_in[8];
    const float* Wg1   = (const float*)d_in[9];
    const float* bg1   = (const float*)d_in[10];
    const float* Wc1   = (const float*)d_in[11];
    const float* bc1   = (const float*)d_in[12];
    const float* sw    = (const float*)d_in[13];
    const float* sb    = (const float*)d_in[14];
    float* out = (float*)d_out;

    // workspace layout (floats), max offset ~11.19M floats = 44.8 MB
    float* w = (float*)d_ws;
    // region A [0 .. 1,200,000 fl): nemb, later aliased by packed recurrent/x1 frags
    float* nemb = w;
    unsigned char* a8 = (unsigned char*)w;
    unsigned char* Wg0f8  = a8;                          //   524,288 B (fp8, paired kt)
    unsigned char* Wc0f8  = a8 + 524288;                 //   262,144 B
    unsigned char* Wg1hf8 = a8 + 786432;                 //   524,288 B
    unsigned char* Wc1hf8 = a8 + 1310720;                //   262,144 B (ends 1,572,864 B)
    unsigned short* Wg1xf = (unsigned short*)(a8 + 1572864);   // 524,288 u16
    unsigned short* Wc1xf = Wg1xf + 524288;                    // 262,144 u16 (ends 3,145,728 B)
    float* nlang = w + 1200000;             // 512
    // xsb bf16 [5000][224] @1,200,512 (560,000 fl), then layer-0 x-side bf16 frags
    unsigned short* xsb   = (unsigned short*)(w + 1200512);    // 1,120,000 u16
    unsigned short* Wg0xf = (unsigned short*)(w + 1760512);    //   229,376 u16 (114,688 fl)
    unsigned short* Wc0xf = (unsigned short*)(w + 1875200);    //   114,688 u16 ( 57,344 fl)
    // region B @2200512 (5.12M fl): Xg0 -> Xg1 (alias) -> swf (alias, after pass2)
    float* Xg0   = w + 2200512;
    float* Xg1   = w + 2200512;
    unsigned short* swf = (unsigned short*)(w + 2200512);      // 8,192,000 u16
    // region C @7320512 (2.56M fl): Xc0 -> Xc1 (alias) -> parts/zt/bsum (alias)
    float* Xc0   = w + 7320512;
    float* Xc1   = w + 7320512;
    float* parts = w + 7320512;             // 1,250,000
    float* ztb   = w + 7320512 + 1250000;   // 5,000
    float* bsum  = w + 7320512 + 1255000;   // 64
    // region D @9880512: h0seq bf16 -> h1o bf16 (alias)
    unsigned short* h0seq = (unsigned short*)(w + 9880512);    // 2,621,440 u16
    unsigned short* h1o   = (unsigned short*)(w + 9880512);    // 2,560,000 u16

    norm_both<<<V_ + 10, 256, 0, stream>>>(emb, lemb, nemb, nlang);
    build_xsb<<<(BT_ * KXP_ + 255) / 256, 256, 0, stream>>>(inp, langs, nemb, nlang, xsb);
    // all 8 weight packs in one dispatcher kernel (overwrites nemb; after build_xsb)
    pack_all<<<1320, 256, 0, stream>>>(Wg0, Wc0, Wg1, Wc1, Wg0f8, Wc0f8, Wg1hf8, Wc1hf8,
                                       Wg1xf, Wc1xf, Wg0xf, Wc0xf);
    // layer-0 input projections (bf16 MFMA, K=224)
    xproj_mfma<16, 7, KXP_><<<313, 256, 0, stream>>>(xsb, Wg0xf, bg0, Xg0, BT_);
    xproj_mfma<8, 7, KXP_><<<313, 256, 0, stream>>>(xsb, Wc0xf, bc0, Xc0, BT_);
    // pass 1: layer-0 recurrence (fp8, r11 ring-2 schedule) -> h0seq (bf16)
    rnn_pass8<<<50, 1024, 0, stream>>>(Xg0, Xc0, Wg0f8, Wc0f8, h0seq);
    // layer-1 input projections from h0seq (bf16 MFMA, K=512)
    xproj_mfma<16, 16, 512><<<313, 256, 0, stream>>>(h0seq, Wg1xf, bg1, Xg1, BT_);
    xproj_mfma<8, 16, 512><<<313, 256, 0, stream>>>(h0seq, Wc1xf, bc1, Xc1, BT_);
    // pass 2: layer-1 recurrence (fp8, r11 ring-2 schedule) -> h1o (bf16)
    rnn_pass8<<<50, 1024, 0, stream>>>(Xg1, Xc1, Wg1hf8, Wc1hf8, h1o);
    // pack softmax weights to bf16 frags (over dead Xg1)
    pack_frags<<<2000, 256, 0, stream>>>(sw, NV_, 16, 500, swf);
    // fused MFMA softmax GEMM + LSE partials + target pick (parts over dead Xc1)
    lse_mfma<<<dim3(125, 79), 256, 0, stream>>>(h1o, swf, sb, tgt, ztb, parts);
    final_nll<<<40, 128, 0, stream>>>(parts, ztb, bsum);
    final_sum<<<1, 64, 0, stream>>>(bsum, out);
}